// Round 7
// baseline (897.996 us; speedup 1.0000x reference)
//
#include <hip/hip_runtime.h>
#include <hip/hip_fp16.h>

typedef _Float16 half_t;
typedef __attribute__((ext_vector_type(8))) _Float16 half8;
typedef __attribute__((ext_vector_type(4))) float f32x4;

#define AS1 __attribute__((address_space(1)))
#define AS3 __attribute__((address_space(3)))

__device__ __forceinline__ void gload16(const half_t* g, half_t* l) {
  __builtin_amdgcn_global_load_lds((const AS1 void*)g, (AS3 void*)l, 16, 0, 0);
}

// ---------------- B-spline basis, UNIFORM grid (h=0.4, knots (j-3)*0.4-1).
__device__ __forceinline__ void bspline8u(float x, float out[8]) {
  float g[12];
#pragma unroll
  for (int j = 0; j < 12; ++j) g[j] = (float)(j - 3) * 0.4f - 1.0f;
  float b[11];
#pragma unroll
  for (int j = 0; j < 11; ++j)
    b[j] = (x >= g[j] && x < g[j + 1]) ? 1.0f : 0.0f;
#pragma unroll
  for (int k = 1; k <= 3; ++k) {
#pragma unroll
    for (int j = 0; j + k < 11; ++j) {
      float rl = 1.0f / (g[j + k] - g[j]);         // constant-folded
      float rr = 1.0f / (g[j + k + 1] - g[j + 1]); // constant-folded
      b[j] = ((x - g[j]) * rl) * b[j] + ((g[j + k + 1] - x) * rr) * b[j + 1];
    }
  }
#pragma unroll
  for (int j = 0; j < 8; ++j) out[j] = b[j];
}

// ---------------- weight conversion: fp32 (base,spline*scaler) -> fp16
__global__ void wconv_kernel(const float* __restrict__ bw, const float* __restrict__ sw,
                             const float* __restrict__ sc, half_t* __restrict__ W,
                             int ibits, int ldw) {
  int idx = blockIdx.x * 256 + threadIdx.x;
  int o = idx >> ibits;
  int i = idx & ((1 << ibits) - 1);
  int c = i >> 10;
  int il = i & 1023;
  float b = bw[idx];
  float scv = sc[idx];
  const float4* svp = (const float4*)sw;
  float4 s0 = svp[(size_t)idx * 2];
  float4 s1 = svp[(size_t)idx * 2 + 1];
  half_t* wrow = W + (size_t)o * ldw + c * 9216;
  wrow[il] = (half_t)b;
  half8 hv;
  hv[0] = (half_t)(s0.x * scv); hv[1] = (half_t)(s0.y * scv);
  hv[2] = (half_t)(s0.z * scv); hv[3] = (half_t)(s0.w * scv);
  hv[4] = (half_t)(s1.x * scv); hv[5] = (half_t)(s1.y * scv);
  hv[6] = (half_t)(s1.z * scv); hv[7] = (half_t)(s1.w * scv);
  *(half8*)&wrow[1024 + il * 8] = hv;
}

// ---------------- activation expansion: v -> [silu(v) | basis(v)[8]] fp16
template <typename ST>
__global__ void expand_kernel(const ST* __restrict__ src, half_t* __restrict__ dst,
                              int Isrc, int i0, int dsub, int kexp) {
  int idx = blockIdx.x * 256 + threadIdx.x;
  int n = idx >> 10;
  int il = idx & 1023;
  float v = (float)src[(size_t)n * Isrc + i0 + il];
  float bs[8];
  bspline8u(v, bs);
  half_t* drow = dst + (size_t)n * kexp + (size_t)dsub * 9216;
  drow[il] = (half_t)(v / (1.0f + expf(-v)));
  half8 hb;
#pragma unroll
  for (int k = 0; k < 8; ++k) hb[k] = (half_t)bs[k];
  *(half8*)&drow[1024 + il * 8] = hb;
}

// ---------------- 8-phase 256x256 GEMM, counted-vmcnt edition (m201/m218
// discipline: vmcnt ONLY at phases 4 and 8, never every phase).
// Stage order: p1:A1(t+1) p2:A0(t+2) p3:B0(t+2) p4:B1(t+2) p5:A1(t+2)
// p6:A0(t+3) p7:B0(t+3) p8:B1(t+3). Ledger-verified:
//  WAR: every stage is >=1 barrier after the last read of old data in its
//   region (A0b0 read p1/staged p2; B0b0 p1/p3; B1b0 p2/p4; A1b0 p3/p5;
//   A0b1 p5/p6; B0b1 p5/p7; B1b1 p6/p8; A1b1 p7/p1-next).
//  RAW: vmcnt(6) at p4 completes all loads through p1 -> protects p5/p6/p7
//   reads (t+1's 4 halves); vmcnt(6) at p8 completes through p5 -> protects
//   next-iter p1/p2/p3 reads (t+2's halves). Worst issue->deadline = 3
//   phases; most 5-7 phases (~1000+cyc, covers HBM latency on streamed A).
// Gray-code quadrant order with persistent frag regs (24 ds_read_b128 per
// K-tile/wave). Tail peeled: vmcnt(0) at p4, no stages except p1.
#define STA(c, t, h)                                                          \
  {                                                                           \
    int r0_ = wid * 8 + (h) * 64;                                             \
    const half_t* g_ = Abase + (size_t)(r0_ + srow) * ldkA +                  \
                       (size_t)(t) * 64 + scol;                               \
    gload16(g_, &As[c][r0_ * 64]);                                            \
    gload16(g_ + (size_t)128 * ldkA, &As[c][(r0_ + 128) * 64]);               \
  }
#define STB(c, t, h)                                                          \
  {                                                                           \
    int r0_ = (wid >> 2) * 64 + (wid & 3) * 8 + (h) * 32;                     \
    const half_t* g_ = Bbase + (size_t)(r0_ + srow) * ldkB +                  \
                       (size_t)(t) * 64 + scol;                               \
    gload16(g_, &Bs[c][r0_ * 64]);                                            \
    gload16(g_ + (size_t)128 * ldkB, &Bs[c][(r0_ + 128) * 64]);               \
  }
#define LOADAF(c, mh)                                                         \
  _Pragma("unroll") for (int a = 0; a < 4; ++a) {                             \
    int row_ = wm * 128 + (mh) * 64 + a * 16 + (lane & 15);                   \
    _Pragma("unroll") for (int ks = 0; ks < 2; ++ks) {                        \
      int ch_ = (ks * 4 + (lane >> 4)) ^ (lane & 7);                          \
      af[a][ks] = *(const half8*)&As[c][row_ * 64 + ch_ * 8];                 \
    }                                                                         \
  }
#define LOADBF(c, nh, bfv)                                                    \
  _Pragma("unroll") for (int b = 0; b < 2; ++b) {                             \
    int row_ = wn * 64 + (nh) * 32 + b * 16 + (lane & 15);                    \
    _Pragma("unroll") for (int ks = 0; ks < 2; ++ks) {                        \
      int ch_ = (ks * 4 + (lane >> 4)) ^ (lane & 7);                          \
      bfv[b][ks] = *(const half8*)&Bs[c][row_ * 64 + ch_ * 8];                \
    }                                                                         \
  }
#define VM6 asm volatile("s_waitcnt vmcnt(6)" ::: "memory");
#define VM0 asm volatile("s_waitcnt vmcnt(0)" ::: "memory");
#define NOVM
#define DOPHASE(mh, nh, bfv, LOADS, STAGE, WAIT)                              \
  do {                                                                        \
    LOADS                                                                     \
    STAGE                                                                     \
    WAIT                                                                      \
    __builtin_amdgcn_s_barrier();                                             \
    __builtin_amdgcn_sched_barrier(0);                                        \
    __builtin_amdgcn_s_setprio(1);                                            \
    _Pragma("unroll") for (int ks = 0; ks < 2; ++ks)                          \
      _Pragma("unroll") for (int a = 0; a < 4; ++a)                           \
        _Pragma("unroll") for (int b = 0; b < 2; ++b)                         \
          acc[(mh) * 4 + a][(nh) * 2 + b] =                                   \
              __builtin_amdgcn_mfma_f32_16x16x32_f16(                         \
                  af[a][ks], bfv[b][ks], acc[(mh) * 4 + a][(nh) * 2 + b],     \
                  0, 0, 0);                                                   \
    __builtin_amdgcn_s_setprio(0);                                            \
    __builtin_amdgcn_s_barrier();                                             \
    __builtin_amdgcn_sched_barrier(0);                                        \
  } while (0)

template <int MODE>
__global__ __launch_bounds__(512, 2) void gemm8_kernel(
    const half_t* __restrict__ A, const half_t* __restrict__ B,
    int ldkA, int ldkB, int kzLen,
    float* __restrict__ Cout, half_t* __restrict__ Hout, int ldc) {
  __shared__ __align__(16) half_t As[2][256 * 64];
  __shared__ __align__(16) half_t Bs[2][256 * 64];

  const int tid = threadIdx.x;
  const int wid = tid >> 6;
  const int lane = tid & 63;
  const int wm = wid >> 2;
  const int wn = wid & 3;

  const half_t* Abase = A + (size_t)blockIdx.x * 256 * ldkA +
                        (size_t)blockIdx.z * kzLen;
  const half_t* Bbase = B + (size_t)blockIdx.y * 256 * ldkB +
                        (size_t)blockIdx.z * kzLen;

  const int srow = lane >> 3;                    // row within 8-row region
  const int scol = ((lane & 7) ^ srow) * 8;      // pre-swizzled 16B chunk

  const int nt = kzLen >> 6;                     // K-tiles (BK=64), even, >=4

  f32x4 acc[8][4] = {};
  half8 af[4][2], bA[2][2], bB[2][2];

  // Prologue: tile0 complete + tile1 {A0,B0,B1}; drain; barrier.
  STA(0, 0, 0); STB(0, 0, 0); STB(0, 0, 1); STA(0, 0, 1);
  STA(1, 1, 0); STB(1, 1, 0); STB(1, 1, 1);
  asm volatile("s_waitcnt vmcnt(0)" ::: "memory");
  __builtin_amdgcn_s_barrier();
  __builtin_amdgcn_sched_barrier(0);

  for (int i = 0; i < (nt >> 1) - 1; ++i) {
    const int t = 2 * i;
    DOPHASE(0, 0, bA, { LOADAF(0, 0) LOADBF(0, 0, bA) }, { STA(1, t + 1, 1); }, NOVM);
    DOPHASE(0, 1, bB, { LOADBF(0, 1, bB) },              { STA(0, t + 2, 0); }, NOVM);
    DOPHASE(1, 1, bB, { LOADAF(0, 1) },                  { STB(0, t + 2, 0); }, NOVM);
    DOPHASE(1, 0, bA, {},                                { STB(0, t + 2, 1); }, VM6);
    DOPHASE(0, 0, bA, { LOADAF(1, 0) LOADBF(1, 0, bA) }, { STA(0, t + 2, 1); }, NOVM);
    DOPHASE(0, 1, bB, { LOADBF(1, 1, bB) },              { STA(1, t + 3, 0); }, NOVM);
    DOPHASE(1, 1, bB, { LOADAF(1, 1) },                  { STB(1, t + 3, 0); }, NOVM);
    DOPHASE(1, 0, bA, {},                                { STB(1, t + 3, 1); }, VM6);
  }
  {
    const int t = nt - 2;  // tail: only t+1's last half still to stage
    DOPHASE(0, 0, bA, { LOADAF(0, 0) LOADBF(0, 0, bA) }, { STA(1, t + 1, 1); }, NOVM);
    DOPHASE(0, 1, bB, { LOADBF(0, 1, bB) },              {},                   NOVM);
    DOPHASE(1, 1, bB, { LOADAF(0, 1) },                  {},                   NOVM);
    DOPHASE(1, 0, bA, {},                                {},                   VM0);
    DOPHASE(0, 0, bA, { LOADAF(1, 0) LOADBF(1, 0, bA) }, {},                   NOVM);
    DOPHASE(0, 1, bB, { LOADBF(1, 1, bB) },              {},                   NOVM);
    DOPHASE(1, 1, bB, { LOADAF(1, 1) },                  {},                   NOVM);
    DOPHASE(1, 0, bA, {},                                {},                   NOVM);
  }

  const int r_lo = (lane >> 4) << 2;
  const int col0 = (int)blockIdx.y * 256 + wn * 64 + (lane & 15);
  const int row00 = (int)blockIdx.x * 256 + wm * 128 + r_lo;
#pragma unroll
  for (int mf = 0; mf < 8; ++mf)
#pragma unroll
    for (int nf = 0; nf < 4; ++nf)
#pragma unroll
      for (int j = 0; j < 4; ++j) {
        float v = acc[mf][nf][j];
        size_t off = (size_t)(row00 + mf * 16 + j) * ldc + col0 + nf * 16;
        if constexpr (MODE == 0) {
          v = 0.5f * v * (1.0f + erff(v * 0.70710678118654752f));
          Hout[off] = (half_t)v;
        } else {
          atomicAdd(&Cout[off], v);
        }
      }
}

extern "C" void kernel_launch(void* const* d_in, const int* in_sizes, int n_in,
                              void* d_out, int out_size, void* d_ws, size_t ws_size,
                              hipStream_t stream) {
  const float* x   = (const float*)d_in[0];
  const float* bw1 = (const float*)d_in[1];
  const float* sw1 = (const float*)d_in[2];
  const float* sc1 = (const float*)d_in[3];
  const float* bw2 = (const float*)d_in[4];
  const float* sw2 = (const float*)d_in[5];
  const float* sc2 = (const float*)d_in[6];
  float* out = (float*)d_out;

  half_t* Wbuf = (half_t*)d_ws;
  const size_t W_HALVES = (size_t)4096 * 9216;     // 75.5MB (W1; W2 same size)
  const size_t A1_HALVES = (size_t)4096 * 9216;    // one 9216-wide A chunk
  const size_t HH_HALVES = (size_t)4096 * 4096;
  int abuf_chunks = 1;
  if (ws_size >= (W_HALVES + A1_HALVES * 4 + HH_HALVES) * sizeof(half_t))
    abuf_chunks = 4;
  else if (ws_size >= (W_HALVES + A1_HALVES * 2 + HH_HALVES) * sizeof(half_t))
    abuf_chunks = 2;
  half_t* Abuf = Wbuf + W_HALVES;
  half_t* Hh   = Abuf + A1_HALVES * abuf_chunks;

  const int T = 256;
  const int NB = (4096 * 1024) / T;

  // out = x (residual baseline); gemm2 atomically accumulates on top.
  hipMemcpyAsync(out, x, (size_t)4096 * 1024 * sizeof(float),
                 hipMemcpyDeviceToDevice, stream);

  // ---- layer 1 ----
  wconv_kernel<<<NB, T, 0, stream>>>(bw1, sw1, sc1, Wbuf, 10, 9216);
  expand_kernel<float><<<NB, T, 0, stream>>>(x, Abuf, 1024, 0, 0, 9216);
  gemm8_kernel<0><<<dim3(16, 16, 1), 512, 0, stream>>>(
      Abuf, Wbuf, 9216, 9216, 9216, nullptr, Hh, 4096);

  // ---- layer 2: W2 rows [o][36864] K-contiguous ----
  wconv_kernel<<<NB, T, 0, stream>>>(bw2, sw2, sc2, Wbuf, 12, 36864);
  if (abuf_chunks == 4) {
    for (int c = 0; c < 4; ++c)
      expand_kernel<half_t><<<NB, T, 0, stream>>>(Hh, Abuf, 4096, c * 1024, c, 36864);
    gemm8_kernel<4><<<dim3(16, 4, 4), 512, 0, stream>>>(
        Abuf, Wbuf, 36864, 36864, 9216, out, nullptr, 1024);
  } else if (abuf_chunks == 2) {
    for (int c = 0; c < 2; ++c) {
      expand_kernel<half_t><<<NB, T, 0, stream>>>(Hh, Abuf, 4096, c * 2048, 0, 18432);
      expand_kernel<half_t><<<NB, T, 0, stream>>>(Hh, Abuf, 4096, c * 2048 + 1024, 1, 18432);
      gemm8_kernel<4><<<dim3(16, 4, 4), 512, 0, stream>>>(
          Abuf, Wbuf + (size_t)c * 18432, 18432, 36864, 4608, out, nullptr, 1024);
    }
  } else {
    for (int c = 0; c < 4; ++c) {
      expand_kernel<half_t><<<NB, T, 0, stream>>>(Hh, Abuf, 4096, c * 1024, 0, 9216);
      gemm8_kernel<4><<<dim3(16, 4, 4), 512, 0, stream>>>(
          Abuf, Wbuf + (size_t)c * 9216, 9216, 36864, 2304, out, nullptr, 1024);
    }
  }
}

// Round 8
// 859.636 us; speedup vs baseline: 1.0446x; 1.0446x over previous
//
#include <hip/hip_runtime.h>
#include <hip/hip_fp16.h>

typedef _Float16 half_t;
typedef __attribute__((ext_vector_type(8))) _Float16 half8;
typedef __attribute__((ext_vector_type(4))) float f32x4;

#define AS1 __attribute__((address_space(1)))
#define AS3 __attribute__((address_space(3)))

__device__ __forceinline__ void gload16(const half_t* g, half_t* l) {
  __builtin_amdgcn_global_load_lds((const AS1 void*)g, (AS3 void*)l, 16, 0, 0);
}

// ---------------- B-spline basis, UNIFORM grid (h=0.4, knots (j-3)*0.4-1).
__device__ __forceinline__ void bspline8u(float x, float out[8]) {
  float g[12];
#pragma unroll
  for (int j = 0; j < 12; ++j) g[j] = (float)(j - 3) * 0.4f - 1.0f;
  float b[11];
#pragma unroll
  for (int j = 0; j < 11; ++j)
    b[j] = (x >= g[j] && x < g[j + 1]) ? 1.0f : 0.0f;
#pragma unroll
  for (int k = 1; k <= 3; ++k) {
#pragma unroll
    for (int j = 0; j + k < 11; ++j) {
      float rl = 1.0f / (g[j + k] - g[j]);         // constant-folded
      float rr = 1.0f / (g[j + k + 1] - g[j + 1]); // constant-folded
      b[j] = ((x - g[j]) * rl) * b[j] + ((g[j + k + 1] - x) * rr) * b[j + 1];
    }
  }
#pragma unroll
  for (int j = 0; j < 8; ++j) out[j] = b[j];
}

// ---------------- weight conversion: fp32 (base,spline*scaler) -> fp16
__global__ void wconv_kernel(const float* __restrict__ bw, const float* __restrict__ sw,
                             const float* __restrict__ sc, half_t* __restrict__ W,
                             int ibits, int ldw) {
  int idx = blockIdx.x * 256 + threadIdx.x;
  int o = idx >> ibits;
  int i = idx & ((1 << ibits) - 1);
  int c = i >> 10;
  int il = i & 1023;
  float b = bw[idx];
  float scv = sc[idx];
  const float4* svp = (const float4*)sw;
  float4 s0 = svp[(size_t)idx * 2];
  float4 s1 = svp[(size_t)idx * 2 + 1];
  half_t* wrow = W + (size_t)o * ldw + c * 9216;
  wrow[il] = (half_t)b;
  half8 hv;
  hv[0] = (half_t)(s0.x * scv); hv[1] = (half_t)(s0.y * scv);
  hv[2] = (half_t)(s0.z * scv); hv[3] = (half_t)(s0.w * scv);
  hv[4] = (half_t)(s1.x * scv); hv[5] = (half_t)(s1.y * scv);
  hv[6] = (half_t)(s1.z * scv); hv[7] = (half_t)(s1.w * scv);
  *(half8*)&wrow[1024 + il * 8] = hv;
}

// ---------------- activation expansion: v -> [silu(v) | basis(v)[8]] fp16
template <typename ST>
__global__ void expand_kernel(const ST* __restrict__ src, half_t* __restrict__ dst,
                              int Isrc, int i0, int dsub, int kexp) {
  int idx = blockIdx.x * 256 + threadIdx.x;
  int n = idx >> 10;
  int il = idx & 1023;
  float v = (float)src[(size_t)n * Isrc + i0 + il];
  float bs[8];
  bspline8u(v, bs);
  half_t* drow = dst + (size_t)n * kexp + (size_t)dsub * 9216;
  drow[il] = (half_t)(v / (1.0f + expf(-v)));
  half8 hb;
#pragma unroll
  for (int k = 0; k < 8; ++k) hb[k] = (half_t)bs[k];
  *(half8*)&drow[1024 + il * 8] = hb;
}

// ---------------- 8-phase 256x256 GEMM, even-read edition.
// Round-6 wait discipline (per-phase vmcnt(6): proven better than p4/p8-only
// in round-7 A/B). New: bA reads rotated into the formerly-empty p4/p8 using
// two parity register sets (bAe even tiles / bAo odd tiles) -> ds_read
// distribution {8,4,8,4,8,4,8,4} instead of {12,4,8,0}: no phase exposes
// 12-read LDS latency behind one barrier, no phase idles the LDS pipe.
// Ledger (completion rule: load issued at phase p completes by p+3's VM6):
//  reads: af0@p1<-prev-p3(c.prev-p6); bB@p2<-prev-p5(c.prev-p8);
//   af1@p3<-prev-p6(c.p1); bAo@p4<-prev-p8(c.p3); af0@p5<-prev-p7(c.p2);
//   bB@p6<-p1(c.p4); af1@p7<-p2(c.p5); bAe@p8<-p4(c.p7). All >=1 phase late.
//  WAR: every stage >=1 barrier after last read of its region (p1:Bs1h1/p6-,
//   p2:As1h1/p7-, p3:As0h0/p1, p4:Bs0h0/p8-, p5:Bs0h1/p2, p6:As0h1/p3,
//   p7:As1h0/p5, p8:Bs1h0/p4).
#define STA(c, t, h)                                                          \
  {                                                                           \
    int r0_ = wid * 8 + (h) * 64;                                             \
    const half_t* g_ = Abase + (size_t)(r0_ + srow) * ldkA +                  \
                       (size_t)(t) * 64 + scol;                               \
    gload16(g_, &As[c][r0_ * 64]);                                            \
    gload16(g_ + (size_t)128 * ldkA, &As[c][(r0_ + 128) * 64]);               \
  }
#define STB(c, t, h)                                                          \
  {                                                                           \
    int r0_ = (wid >> 2) * 64 + (wid & 3) * 8 + (h) * 32;                     \
    const half_t* g_ = Bbase + (size_t)(r0_ + srow) * ldkB +                  \
                       (size_t)(t) * 64 + scol;                               \
    gload16(g_, &Bs[c][r0_ * 64]);                                            \
    gload16(g_ + (size_t)128 * ldkB, &Bs[c][(r0_ + 128) * 64]);               \
  }
#define LOADAF(c, mh)                                                         \
  _Pragma("unroll") for (int a = 0; a < 4; ++a) {                             \
    int row_ = wm * 128 + (mh) * 64 + a * 16 + (lane & 15);                   \
    _Pragma("unroll") for (int ks = 0; ks < 2; ++ks) {                        \
      int ch_ = (ks * 4 + (lane >> 4)) ^ (lane & 7);                          \
      af[a][ks] = *(const half8*)&As[c][row_ * 64 + ch_ * 8];                 \
    }                                                                         \
  }
#define LOADBF(c, nh, bfv)                                                    \
  _Pragma("unroll") for (int b = 0; b < 2; ++b) {                             \
    int row_ = wn * 64 + (nh) * 32 + b * 16 + (lane & 15);                    \
    _Pragma("unroll") for (int ks = 0; ks < 2; ++ks) {                        \
      int ch_ = (ks * 4 + (lane >> 4)) ^ (lane & 7);                          \
      bfv[b][ks] = *(const half8*)&Bs[c][row_ * 64 + ch_ * 8];                \
    }                                                                         \
  }
#define VM6 asm volatile("s_waitcnt vmcnt(6)" ::: "memory");
#define VM0 asm volatile("s_waitcnt vmcnt(0)" ::: "memory");
#define NOVM
#define DOPHASE(mh, nh, bfv, LOADS, STAGE, WAIT)                              \
  do {                                                                        \
    LOADS                                                                     \
    STAGE                                                                     \
    WAIT                                                                      \
    __builtin_amdgcn_s_barrier();                                             \
    __builtin_amdgcn_sched_barrier(0);                                        \
    __builtin_amdgcn_s_setprio(1);                                            \
    _Pragma("unroll") for (int ks = 0; ks < 2; ++ks)                          \
      _Pragma("unroll") for (int a = 0; a < 4; ++a)                           \
        _Pragma("unroll") for (int b = 0; b < 2; ++b)                         \
          acc[(mh) * 4 + a][(nh) * 2 + b] =                                   \
              __builtin_amdgcn_mfma_f32_16x16x32_f16(                         \
                  af[a][ks], bfv[b][ks], acc[(mh) * 4 + a][(nh) * 2 + b],     \
                  0, 0, 0);                                                   \
    __builtin_amdgcn_s_setprio(0);                                            \
    __builtin_amdgcn_s_barrier();                                             \
    __builtin_amdgcn_sched_barrier(0);                                        \
  } while (0)

template <int MODE>
__global__ __launch_bounds__(512, 2) void gemm8_kernel(
    const half_t* __restrict__ A, const half_t* __restrict__ B,
    int ldkA, int ldkB, int kzLen,
    float* __restrict__ Cout, half_t* __restrict__ Hout, int ldc) {
  __shared__ __align__(16) half_t As[2][256 * 64];
  __shared__ __align__(16) half_t Bs[2][256 * 64];

  const int tid = threadIdx.x;
  const int wid = tid >> 6;
  const int lane = tid & 63;
  const int wm = wid >> 2;
  const int wn = wid & 3;

  const half_t* Abase = A + (size_t)blockIdx.x * 256 * ldkA +
                        (size_t)blockIdx.z * kzLen;
  const half_t* Bbase = B + (size_t)blockIdx.y * 256 * ldkB +
                        (size_t)blockIdx.z * kzLen;

  const int srow = lane >> 3;                    // row within 8-row region
  const int scol = ((lane & 7) ^ srow) * 8;      // pre-swizzled 16B chunk

  const int nt = kzLen >> 6;                     // K-tiles (BK=64), even, >=4

  f32x4 acc[8][4] = {};
  half8 af[4][2], bAe[2][2], bAo[2][2], bB[2][2];

  // Prologue: tile0 complete + tile1 {A-h0, B-h0}; drain; barrier; preload bAe.
  STA(0, 0, 0); STB(0, 0, 0); STB(0, 0, 1); STA(0, 0, 1);
  STA(1, 1, 0); STB(1, 1, 0);
  asm volatile("s_waitcnt vmcnt(0)" ::: "memory");
  __builtin_amdgcn_s_barrier();
  __builtin_amdgcn_sched_barrier(0);
  LOADBF(0, 0, bAe)

  for (int i = 0; i < (nt >> 1) - 1; ++i) {
    const int t = 2 * i;
    DOPHASE(0, 0, bAe, { LOADAF(0, 0) },      { STB(1, t + 1, 1); }, VM6);
    DOPHASE(0, 1, bB,  { LOADBF(0, 1, bB) },  { STA(1, t + 1, 1); }, VM6);
    DOPHASE(1, 1, bB,  { LOADAF(0, 1) },      { STA(0, t + 2, 0); }, VM6);
    DOPHASE(1, 0, bAe, { LOADBF(1, 0, bAo) }, { STB(0, t + 2, 0); }, VM6);
    DOPHASE(0, 0, bAo, { LOADAF(1, 0) },      { STB(0, t + 2, 1); }, VM6);
    DOPHASE(0, 1, bB,  { LOADBF(1, 1, bB) },  { STA(0, t + 2, 1); }, VM6);
    DOPHASE(1, 1, bB,  { LOADAF(1, 1) },      { STA(1, t + 3, 0); }, VM6);
    DOPHASE(1, 0, bAo, { LOADBF(0, 0, bAe) }, { STB(1, t + 3, 0); }, VM6);
  }
  {
    const int t = nt - 2;  // tail: only t+1's remaining halves staged
    DOPHASE(0, 0, bAe, { LOADAF(0, 0) },      { STB(1, t + 1, 1); }, VM6);
    DOPHASE(0, 1, bB,  { LOADBF(0, 1, bB) },  { STA(1, t + 1, 1); }, VM6);
    DOPHASE(1, 1, bB,  { LOADAF(0, 1) },      {},                   VM0);
    DOPHASE(1, 0, bAe, { LOADBF(1, 0, bAo) }, {},                   NOVM);
    DOPHASE(0, 0, bAo, { LOADAF(1, 0) },      {},                   NOVM);
    DOPHASE(0, 1, bB,  { LOADBF(1, 1, bB) },  {},                   NOVM);
    DOPHASE(1, 1, bB,  { LOADAF(1, 1) },      {},                   NOVM);
    DOPHASE(1, 0, bAo, {},                    {},                   NOVM);
  }

  const int r_lo = (lane >> 4) << 2;
  const int col0 = (int)blockIdx.y * 256 + wn * 64 + (lane & 15);
  const int row00 = (int)blockIdx.x * 256 + wm * 128 + r_lo;
#pragma unroll
  for (int mf = 0; mf < 8; ++mf)
#pragma unroll
    for (int nf = 0; nf < 4; ++nf)
#pragma unroll
      for (int j = 0; j < 4; ++j) {
        float v = acc[mf][nf][j];
        size_t off = (size_t)(row00 + mf * 16 + j) * ldc + col0 + nf * 16;
        if constexpr (MODE == 0) {
          v = 0.5f * v * (1.0f + erff(v * 0.70710678118654752f));
          Hout[off] = (half_t)v;
        } else {
          atomicAdd(&Cout[off], v);
        }
      }
}

extern "C" void kernel_launch(void* const* d_in, const int* in_sizes, int n_in,
                              void* d_out, int out_size, void* d_ws, size_t ws_size,
                              hipStream_t stream) {
  const float* x   = (const float*)d_in[0];
  const float* bw1 = (const float*)d_in[1];
  const float* sw1 = (const float*)d_in[2];
  const float* sc1 = (const float*)d_in[3];
  const float* bw2 = (const float*)d_in[4];
  const float* sw2 = (const float*)d_in[5];
  const float* sc2 = (const float*)d_in[6];
  float* out = (float*)d_out;

  half_t* Wbuf = (half_t*)d_ws;
  const size_t W_HALVES = (size_t)4096 * 9216;     // 75.5MB (W1; W2 same size)
  const size_t A1_HALVES = (size_t)4096 * 9216;    // one 9216-wide A chunk
  const size_t HH_HALVES = (size_t)4096 * 4096;
  int abuf_chunks = 1;
  if (ws_size >= (W_HALVES + A1_HALVES * 4 + HH_HALVES) * sizeof(half_t))
    abuf_chunks = 4;
  else if (ws_size >= (W_HALVES + A1_HALVES * 2 + HH_HALVES) * sizeof(half_t))
    abuf_chunks = 2;
  half_t* Abuf = Wbuf + W_HALVES;
  half_t* Hh   = Abuf + A1_HALVES * abuf_chunks;

  const int T = 256;
  const int NB = (4096 * 1024) / T;

  // out = x (residual baseline); gemm2 atomically accumulates on top.
  hipMemcpyAsync(out, x, (size_t)4096 * 1024 * sizeof(float),
                 hipMemcpyDeviceToDevice, stream);

  // ---- layer 1 ----
  wconv_kernel<<<NB, T, 0, stream>>>(bw1, sw1, sc1, Wbuf, 10, 9216);
  expand_kernel<float><<<NB, T, 0, stream>>>(x, Abuf, 1024, 0, 0, 9216);
  gemm8_kernel<0><<<dim3(16, 16, 1), 512, 0, stream>>>(
      Abuf, Wbuf, 9216, 9216, 9216, nullptr, Hh, 4096);

  // ---- layer 2: W2 rows [o][36864] K-contiguous ----
  wconv_kernel<<<NB, T, 0, stream>>>(bw2, sw2, sc2, Wbuf, 12, 36864);
  if (abuf_chunks == 4) {
    for (int c = 0; c < 4; ++c)
      expand_kernel<half_t><<<NB, T, 0, stream>>>(Hh, Abuf, 4096, c * 1024, c, 36864);
    gemm8_kernel<4><<<dim3(16, 4, 4), 512, 0, stream>>>(
        Abuf, Wbuf, 36864, 36864, 9216, out, nullptr, 1024);
  } else if (abuf_chunks == 2) {
    for (int c = 0; c < 2; ++c) {
      expand_kernel<half_t><<<NB, T, 0, stream>>>(Hh, Abuf, 4096, c * 2048, 0, 18432);
      expand_kernel<half_t><<<NB, T, 0, stream>>>(Hh, Abuf, 4096, c * 2048 + 1024, 1, 18432);
      gemm8_kernel<4><<<dim3(16, 4, 4), 512, 0, stream>>>(
          Abuf, Wbuf + (size_t)c * 18432, 18432, 36864, 4608, out, nullptr, 1024);
    }
  } else {
    for (int c = 0; c < 4; ++c) {
      expand_kernel<half_t><<<NB, T, 0, stream>>>(Hh, Abuf, 4096, c * 1024, 0, 9216);
      gemm8_kernel<4><<<dim3(16, 4, 4), 512, 0, stream>>>(
          Abuf, Wbuf + (size_t)c * 9216, 9216, 36864, 2304, out, nullptr, 1024);
    }
  }
}

// Round 9
// 822.500 us; speedup vs baseline: 1.0918x; 1.0451x over previous
//
#include <hip/hip_runtime.h>
#include <hip/hip_fp16.h>

typedef _Float16 half_t;
typedef __attribute__((ext_vector_type(8))) _Float16 half8;
typedef __attribute__((ext_vector_type(4))) float f32x4;

#define AS1 __attribute__((address_space(1)))
#define AS3 __attribute__((address_space(3)))

__device__ __forceinline__ void gload16(const half_t* g, half_t* l) {
  __builtin_amdgcn_global_load_lds((const AS1 void*)g, (AS3 void*)l, 16, 0, 0);
}

// ---------------- B-spline basis, UNIFORM grid (h=0.4, knots (j-3)*0.4-1).
__device__ __forceinline__ void bspline8u(float x, float out[8]) {
  float g[12];
#pragma unroll
  for (int j = 0; j < 12; ++j) g[j] = (float)(j - 3) * 0.4f - 1.0f;
  float b[11];
#pragma unroll
  for (int j = 0; j < 11; ++j)
    b[j] = (x >= g[j] && x < g[j + 1]) ? 1.0f : 0.0f;
#pragma unroll
  for (int k = 1; k <= 3; ++k) {
#pragma unroll
    for (int j = 0; j + k < 11; ++j) {
      float rl = 1.0f / (g[j + k] - g[j]);         // constant-folded
      float rr = 1.0f / (g[j + k + 1] - g[j + 1]); // constant-folded
      b[j] = ((x - g[j]) * rl) * b[j] + ((g[j + k + 1] - x) * rr) * b[j + 1];
    }
  }
#pragma unroll
  for (int j = 0; j < 8; ++j) out[j] = b[j];
}

// ---------------- weight conversion: fp32 (base,spline*scaler) -> fp16
// Row layout per output o: ldw halves (PADDED: data in [0, nchunks*9216),
// 64-half pad at row end to break power-of-2 channel aliasing).
__global__ void wconv_kernel(const float* __restrict__ bw, const float* __restrict__ sw,
                             const float* __restrict__ sc, half_t* __restrict__ W,
                             int ibits, int ldw) {
  int idx = blockIdx.x * 256 + threadIdx.x;
  int o = idx >> ibits;
  int i = idx & ((1 << ibits) - 1);
  int c = i >> 10;
  int il = i & 1023;
  float b = bw[idx];
  float scv = sc[idx];
  const float4* svp = (const float4*)sw;
  float4 s0 = svp[(size_t)idx * 2];
  float4 s1 = svp[(size_t)idx * 2 + 1];
  half_t* wrow = W + (size_t)o * ldw + c * 9216;
  wrow[il] = (half_t)b;
  half8 hv;
  hv[0] = (half_t)(s0.x * scv); hv[1] = (half_t)(s0.y * scv);
  hv[2] = (half_t)(s0.z * scv); hv[3] = (half_t)(s0.w * scv);
  hv[4] = (half_t)(s1.x * scv); hv[5] = (half_t)(s1.y * scv);
  hv[6] = (half_t)(s1.z * scv); hv[7] = (half_t)(s1.w * scv);
  *(half8*)&wrow[1024 + il * 8] = hv;
}

// ---------------- activation expansion: v -> [silu(v) | basis(v)[8]] fp16
template <typename ST>
__global__ void expand_kernel(const ST* __restrict__ src, half_t* __restrict__ dst,
                              int Isrc, int i0, int dsub, int kexp) {
  int idx = blockIdx.x * 256 + threadIdx.x;
  int n = idx >> 10;
  int il = idx & 1023;
  float v = (float)src[(size_t)n * Isrc + i0 + il];
  float bs[8];
  bspline8u(v, bs);
  half_t* drow = dst + (size_t)n * kexp + (size_t)dsub * 9216;
  drow[il] = (half_t)(v / (1.0f + expf(-v)));
  half8 hb;
#pragma unroll
  for (int k = 0; k < 8; ++k) hb[k] = (half_t)bs[k];
  *(half8*)&drow[1024 + il * 8] = hb;
}

// ---------------- 8-phase 256x256 GEMM (round-6 schedule, proven best of 3
// wait-discipline variants). Gray-code quadrant order with persistent frag
// regs (24 ds_read_b128 per K-tile/wave), per-phase vmcnt(6), peeled tail
// with exact counted waits 6,6,6,6,4,2,0,0.
// NEW (round 9): callers pass PADDED ldk (row stride = data + 64 halves) so
// the 8 rows a wave stages per gload-pair are offset by odd multiples of
// 128B -> no HBM-channel / L2-set aliasing on the staged streams (round-8
// analysis: 6.5 vs m201's 13.5 TB/s staging at identical per-phase work).
#define STA(c, t, h)                                                          \
  {                                                                           \
    int r0_ = wid * 8 + (h) * 64;                                             \
    const half_t* g_ = Abase + (size_t)(r0_ + srow) * ldkA +                  \
                       (size_t)(t) * 64 + scol;                               \
    gload16(g_, &As[c][r0_ * 64]);                                            \
    gload16(g_ + (size_t)128 * ldkA, &As[c][(r0_ + 128) * 64]);               \
  }
#define STB(c, t, h)                                                          \
  {                                                                           \
    int r0_ = (wid >> 2) * 64 + (wid & 3) * 8 + (h) * 32;                     \
    const half_t* g_ = Bbase + (size_t)(r0_ + srow) * ldkB +                  \
                       (size_t)(t) * 64 + scol;                               \
    gload16(g_, &Bs[c][r0_ * 64]);                                            \
    gload16(g_ + (size_t)128 * ldkB, &Bs[c][(r0_ + 128) * 64]);               \
  }
#define LOADAF(c, mh)                                                         \
  _Pragma("unroll") for (int a = 0; a < 4; ++a) {                             \
    int row_ = wm * 128 + (mh) * 64 + a * 16 + (lane & 15);                   \
    _Pragma("unroll") for (int ks = 0; ks < 2; ++ks) {                        \
      int ch_ = (ks * 4 + (lane >> 4)) ^ (lane & 7);                          \
      af[a][ks] = *(const half8*)&As[c][row_ * 64 + ch_ * 8];                 \
    }                                                                         \
  }
#define LOADBF(c, nh, bfv)                                                    \
  _Pragma("unroll") for (int b = 0; b < 2; ++b) {                             \
    int row_ = wn * 64 + (nh) * 32 + b * 16 + (lane & 15);                    \
    _Pragma("unroll") for (int ks = 0; ks < 2; ++ks) {                        \
      int ch_ = (ks * 4 + (lane >> 4)) ^ (lane & 7);                          \
      bfv[b][ks] = *(const half8*)&Bs[c][row_ * 64 + ch_ * 8];                \
    }                                                                         \
  }
#define DOPHASE(W, mh, nh, bfv, LOADS, STAGE)                                 \
  do {                                                                        \
    LOADS                                                                     \
    STAGE                                                                     \
    asm volatile("s_waitcnt vmcnt(" #W ")" ::: "memory");                     \
    __builtin_amdgcn_s_barrier();                                             \
    __builtin_amdgcn_sched_barrier(0);                                        \
    __builtin_amdgcn_s_setprio(1);                                            \
    _Pragma("unroll") for (int ks = 0; ks < 2; ++ks)                          \
      _Pragma("unroll") for (int a = 0; a < 4; ++a)                           \
        _Pragma("unroll") for (int b = 0; b < 2; ++b)                         \
          acc[(mh) * 4 + a][(nh) * 2 + b] =                                   \
              __builtin_amdgcn_mfma_f32_16x16x32_f16(                         \
                  af[a][ks], bfv[b][ks], acc[(mh) * 4 + a][(nh) * 2 + b],     \
                  0, 0, 0);                                                   \
    __builtin_amdgcn_s_setprio(0);                                            \
    __builtin_amdgcn_s_barrier();                                             \
    __builtin_amdgcn_sched_barrier(0);                                        \
  } while (0)

template <int MODE>
__global__ __launch_bounds__(512, 2) void gemm8_kernel(
    const half_t* __restrict__ A, const half_t* __restrict__ B,
    int ldkA, int ldkB, int kzLen,
    float* __restrict__ Cout, half_t* __restrict__ Hout, int ldc) {
  __shared__ __align__(16) half_t As[2][256 * 64];
  __shared__ __align__(16) half_t Bs[2][256 * 64];

  const int tid = threadIdx.x;
  const int wid = tid >> 6;
  const int lane = tid & 63;
  const int wm = wid >> 2;
  const int wn = wid & 3;

  const half_t* Abase = A + (size_t)blockIdx.x * 256 * ldkA +
                        (size_t)blockIdx.z * kzLen;
  const half_t* Bbase = B + (size_t)blockIdx.y * 256 * ldkB +
                        (size_t)blockIdx.z * kzLen;

  const int srow = lane >> 3;                    // row within 8-row region
  const int scol = ((lane & 7) ^ srow) * 8;      // pre-swizzled 16B chunk

  const int nt = kzLen >> 6;                     // K-tiles (BK=64), even, >=4

  f32x4 acc[8][4] = {};
  half8 af[4][2], bA[2][2], bB[2][2];

  // Prologue: tile0 complete + tile1 {Am0,Bn0}; drain; barrier.
  STA(0, 0, 0); STB(0, 0, 0); STB(0, 0, 1); STA(0, 0, 1);
  STA(1, 1, 0); STB(1, 1, 0);
  asm volatile("s_waitcnt vmcnt(0)" ::: "memory");
  __builtin_amdgcn_s_barrier();
  __builtin_amdgcn_sched_barrier(0);

  for (int i = 0; i < (nt >> 1) - 1; ++i) {
    const int t = 2 * i;
    DOPHASE(6, 0, 0, bA, { LOADAF(0, 0) LOADBF(0, 0, bA) }, { STB(1, t + 1, 1); });
    DOPHASE(6, 0, 1, bB, { LOADBF(0, 1, bB) },              { STA(1, t + 1, 1); });
    DOPHASE(6, 1, 1, bB, { LOADAF(0, 1) },                  { STA(0, t + 2, 0); });
    DOPHASE(6, 1, 0, bA, {},                                { STB(0, t + 2, 0); });
    DOPHASE(6, 0, 0, bA, { LOADAF(1, 0) LOADBF(1, 0, bA) }, { STB(0, t + 2, 1); });
    DOPHASE(6, 0, 1, bB, { LOADBF(1, 1, bB) },              { STA(0, t + 2, 1); });
    DOPHASE(6, 1, 1, bB, { LOADAF(1, 1) },                  { STA(1, t + 3, 0); });
    DOPHASE(6, 1, 0, bA, {},                                { STB(1, t + 3, 0); });
  }
  {
    const int t = nt - 2;  // tail: stages only t+1's remaining halves
    DOPHASE(6, 0, 0, bA, { LOADAF(0, 0) LOADBF(0, 0, bA) }, { STB(1, t + 1, 1); });
    DOPHASE(6, 0, 1, bB, { LOADBF(0, 1, bB) },              { STA(1, t + 1, 1); });
    DOPHASE(6, 1, 1, bB, { LOADAF(0, 1) },                  {});
    DOPHASE(6, 1, 0, bA, {},                                {});
    DOPHASE(4, 0, 0, bA, { LOADAF(1, 0) LOADBF(1, 0, bA) }, {});
    DOPHASE(2, 0, 1, bB, { LOADBF(1, 1, bB) },              {});
    DOPHASE(0, 1, 1, bB, { LOADAF(1, 1) },                  {});
    DOPHASE(0, 1, 0, bA, {},                                {});
  }

  const int r_lo = (lane >> 4) << 2;
  const int col0 = (int)blockIdx.y * 256 + wn * 64 + (lane & 15);
  const int row00 = (int)blockIdx.x * 256 + wm * 128 + r_lo;
#pragma unroll
  for (int mf = 0; mf < 8; ++mf)
#pragma unroll
    for (int nf = 0; nf < 4; ++nf)
#pragma unroll
      for (int j = 0; j < 4; ++j) {
        float v = acc[mf][nf][j];
        size_t off = (size_t)(row00 + mf * 16 + j) * ldc + col0 + nf * 16;
        if constexpr (MODE == 0) {
          v = 0.5f * v * (1.0f + erff(v * 0.70710678118654752f));
          Hout[off] = (half_t)v;
        } else {
          atomicAdd(&Cout[off], v);
        }
      }
}

extern "C" void kernel_launch(void* const* d_in, const int* in_sizes, int n_in,
                              void* d_out, int out_size, void* d_ws, size_t ws_size,
                              hipStream_t stream) {
  const float* x   = (const float*)d_in[0];
  const float* bw1 = (const float*)d_in[1];
  const float* sw1 = (const float*)d_in[2];
  const float* sc1 = (const float*)d_in[3];
  const float* bw2 = (const float*)d_in[4];
  const float* sw2 = (const float*)d_in[5];
  const float* sc2 = (const float*)d_in[6];
  float* out = (float*)d_out;

  // Padded row strides (data + 64 halves = +128B) to break power-of-2
  // channel/set aliasing on the GEMM staging streams.
  const int LDK1 = 9216 + 64;    // layer-1 A and W rows
  const int LDK2 = 36864 + 64;   // layer-2 full-K rows (4 chunks of 9216)
  const int LDK2H = 18432 + 64;  // layer-2 2-chunk rows

  half_t* Wbuf = (half_t*)d_ws;
  const size_t W_HALVES  = (size_t)4096 * LDK1;   // holds W1 (4096xLDK1) and W2 (1024xLDK2)
  const size_t AF_HALVES = (size_t)4096 * LDK2;   // full-mode A
  const size_t A2_HALVES = (size_t)4096 * LDK2H;  // 2-chunk-mode A
  const size_t A1_HALVES = (size_t)4096 * LDK1;   // 1-chunk-mode A
  const size_t HH_HALVES = (size_t)4096 * 4096;
  int abuf_chunks = 1;
  if (ws_size >= (W_HALVES + AF_HALVES + HH_HALVES) * sizeof(half_t))
    abuf_chunks = 4;
  else if (ws_size >= (W_HALVES + A2_HALVES + HH_HALVES) * sizeof(half_t))
    abuf_chunks = 2;
  half_t* Abuf = Wbuf + W_HALVES;
  half_t* Hh   = Abuf + (abuf_chunks == 4 ? AF_HALVES
                         : abuf_chunks == 2 ? A2_HALVES : A1_HALVES);

  const int T = 256;
  const int NB = (4096 * 1024) / T;

  // out = x (residual baseline); gemm2 atomically accumulates on top.
  hipMemcpyAsync(out, x, (size_t)4096 * 1024 * sizeof(float),
                 hipMemcpyDeviceToDevice, stream);

  // ---- layer 1 ----
  wconv_kernel<<<NB, T, 0, stream>>>(bw1, sw1, sc1, Wbuf, 10, LDK1);
  expand_kernel<float><<<NB, T, 0, stream>>>(x, Abuf, 1024, 0, 0, LDK1);
  gemm8_kernel<0><<<dim3(16, 16, 1), 512, 0, stream>>>(
      Abuf, Wbuf, LDK1, LDK1, 9216, nullptr, Hh, 4096);

  // ---- layer 2: W2 rows [o][LDK2], data K-contiguous in [0,36864) ----
  wconv_kernel<<<NB, T, 0, stream>>>(bw2, sw2, sc2, Wbuf, 12, LDK2);
  if (abuf_chunks == 4) {
    for (int c = 0; c < 4; ++c)
      expand_kernel<half_t><<<NB, T, 0, stream>>>(Hh, Abuf, 4096, c * 1024, c, LDK2);
    gemm8_kernel<4><<<dim3(16, 4, 4), 512, 0, stream>>>(
        Abuf, Wbuf, LDK2, LDK2, 9216, out, nullptr, 1024);
  } else if (abuf_chunks == 2) {
    for (int c = 0; c < 2; ++c) {
      expand_kernel<half_t><<<NB, T, 0, stream>>>(Hh, Abuf, 4096, c * 2048, 0, LDK2H);
      expand_kernel<half_t><<<NB, T, 0, stream>>>(Hh, Abuf, 4096, c * 2048 + 1024, 1, LDK2H);
      gemm8_kernel<4><<<dim3(16, 4, 4), 512, 0, stream>>>(
          Abuf, Wbuf + (size_t)c * 18432, LDK2H, LDK2, 4608, out, nullptr, 1024);
    }
  } else {
    for (int c = 0; c < 4; ++c) {
      expand_kernel<half_t><<<NB, T, 0, stream>>>(Hh, Abuf, 4096, c * 1024, 0, LDK1);
      gemm8_kernel<4><<<dim3(16, 4, 4), 512, 0, stream>>>(
          Abuf, Wbuf + (size_t)c * 9216, LDK1, LDK2, 2304, out, nullptr, 1024);
    }
  }
}